// Round 2
// baseline (4065.623 us; speedup 1.0000x reference)
//
#include <hip/hip_runtime.h>
#include <hip/hip_bf16.h>
#include <cstdint>

static constexpr int N_  = 16384;
static constexpr int E_  = 131072;
static constexpr int D_  = 768;
static constexpr int D2_ = 1536;
static constexpr int DSQ_ = D_ * D_;

// ---------------- workspace layout (bytes) ----------------
static constexpr size_t OFF_X    = 0;                       // N*D fp32   = 50331648
static constexpr size_t OFF_WC   = 50331648;                // 12*D*D fp32 = 28311552
static constexpr size_t OFF_HT   = 78643200;                // N*D fp32   = 50331648
static constexpr size_t OFF_N    = 128974848;               // N*2D fp32  = 100663296
static constexpr size_t OFF_TG   = 229638144;               // E int32    = 524288
static constexpr size_t OFF_CNT  = 230162432;               // N*4 int32  = 262144
static constexpr size_t OFF_BC   = 230424576;               // 512 int32
static constexpr size_t OFF_SCAN = 230426624;               // 513 int32

__device__ __forceinline__ float wave_sum(float v) {
#pragma unroll
  for (int o = 32; o; o >>= 1) v += __shfl_down(v, o, 64);
  return v;
}

// Wc[f,t] = sum_b coeff_f[t,b] * W_f[b]
__global__ __launch_bounds__(256) void combine_w_kernel(
    const float* __restrict__ Wt, const float* __restrict__ ct,
    const float* __restrict__ Wu, const float* __restrict__ cu,
    const float* __restrict__ Wd, const float* __restrict__ cd,
    float* __restrict__ Wc) {
  int i  = blockIdx.x * 256 + threadIdx.x;   // < D*D
  int ft = blockIdx.y;                        // 0..11
  int f = ft >> 2, t = ft & 3;
  const float* W = (f == 0) ? Wt : ((f == 1) ? Wu : Wd);
  const float* c = ((f == 0) ? ct : ((f == 1) ? cu : cd)) + t * 3;
  Wc[(size_t)ft * DSQ_ + i] =
      c[0] * W[i] + c[1] * W[DSQ_ + i] + c[2] * W[2 * DSQ_ + i];
}

__global__ __launch_bounds__(256) void ln_kernel(
    const float* __restrict__ h, const float* __restrict__ gamma,
    const float* __restrict__ beta, float* __restrict__ x) {
  int v = blockIdx.x, tid = threadIdx.x;
  const float* hr = h + (size_t)v * D_;
  float e0 = hr[tid], e1 = hr[tid + 256], e2 = hr[tid + 512];
  float s = e0 + e1 + e2;
  float q = e0 * e0 + e1 * e1 + e2 * e2;
  __shared__ float red[8];
  __shared__ float mv[2];
  float ws_ = wave_sum(s), wq = wave_sum(q);
  int lane = tid & 63, w = tid >> 6;
  if (lane == 0) { red[w] = ws_; red[4 + w] = wq; }
  __syncthreads();
  if (tid == 0) {
    float S = red[0] + red[1] + red[2] + red[3];
    float Q = red[4] + red[5] + red[6] + red[7];
    float mu = S * (1.0f / D_);
    float var = Q * (1.0f / D_) - mu * mu;
    mv[0] = mu;
    mv[1] = rsqrtf(var + 1e-5f);
  }
  __syncthreads();
  float mu = mv[0], rstd = mv[1];
  float* xr = x + (size_t)v * D_;
  xr[tid]       = (e0 - mu) * rstd * gamma[tid]       + beta[tid];
  xr[tid + 256] = (e1 - mu) * rstd * gamma[tid + 256] + beta[tid + 256];
  xr[tid + 512] = (e2 - mu) * rstd * gamma[tid + 512] + beta[tid + 512];
}

// per-block hete counts + (dst,etype) histogram
__global__ __launch_bounds__(256) void edge_a_kernel(
    const int* __restrict__ hete, const int* __restrict__ dst,
    const int* __restrict__ etype, int* __restrict__ blockcnt,
    int* __restrict__ cnt4) {
  int j = blockIdx.x * 256 + threadIdx.x;
  int flag = hete[j] > 0;
  unsigned long long m = __ballot(flag);
  __shared__ int wsum[4];
  int lane = threadIdx.x & 63, w = threadIdx.x >> 6;
  if (lane == 0) wsum[w] = __popcll(m);
  __syncthreads();
  if (threadIdx.x == 0)
    blockcnt[blockIdx.x] = wsum[0] + wsum[1] + wsum[2] + wsum[3];
  atomicAdd(&cnt4[dst[j] * 4 + etype[j]], 1);
}

// single-block scan over 512 block counts -> exclusive offsets + total K
__global__ __launch_bounds__(512) void scan_kernel(
    const int* __restrict__ blockcnt, int* __restrict__ scanout) {
  __shared__ int s[512];
  int t = threadIdx.x;
  int v = blockcnt[t];
  s[t] = v;
  __syncthreads();
  for (int o = 1; o < 512; o <<= 1) {
    int add = (t >= o) ? s[t - o] : 0;
    __syncthreads();
    s[t] += add;
    __syncthreads();
  }
  scanout[t] = s[t] - v;             // exclusive prefix
  if (t == 511) scanout[512] = s[511];  // total hete count K
}

// target[j] = dst[perm_inv[j]]
__global__ __launch_bounds__(256) void edge_b_kernel(
    const int* __restrict__ hete, const int* __restrict__ dst,
    const int* __restrict__ scanout, int* __restrict__ target) {
  int j = blockIdx.x * 256 + threadIdx.x;
  int flag = hete[j] > 0;
  unsigned long long m = __ballot(flag);
  __shared__ int wsum[4];
  int lane = threadIdx.x & 63, w = threadIdx.x >> 6;
  if (lane == 0) wsum[w] = __popcll(m);
  __syncthreads();
  int wpre = 0;
#pragma unroll
  for (int i = 0; i < 4; i++) wpre += (i < w) ? wsum[i] : 0;
  int lpre = __popcll(m & ((1ull << lane) - 1ull));
  int hcum = scanout[blockIdx.x] + wpre + lpre;  // # hete edges with idx < j
  int K = scanout[512];
  int e = flag ? hcum : (K + j - hcum);
  target[j] = dst[e];
}

// C[M,N] = op(A[M,K] @ B[K,N] (+bias)), op = relu if RELU
template <bool RELU, bool BIAS>
__global__ __launch_bounds__(256) void gemm_kernel(
    const float* __restrict__ A, const float* __restrict__ B,
    const float* __restrict__ bias, float* __restrict__ C,
    int M, int N, int K) {
  __shared__ float As[16][64];
  __shared__ float Bs[16][64];
  int tid = threadIdx.x;
  int tx = tid & 15, ty = tid >> 4;
  int row0 = blockIdx.y * 64, col0 = blockIdx.x * 64;
  int la_r = tid >> 2, la_k = (tid & 3) * 4;
  int lb_k = tid >> 4, lb_n = (tid & 15) * 4;
  const float* Ap = A + (size_t)(row0 + la_r) * K + la_k;
  const float* Bp = B + (size_t)lb_k * N + col0 + lb_n;
  float acc[4][4] = {};
  for (int k0 = 0; k0 < K; k0 += 16) {
    float4 a4 = *(const float4*)(Ap + k0);
    float4 b4 = *(const float4*)(Bp + (size_t)k0 * N);
    __syncthreads();
    As[la_k + 0][la_r] = a4.x;
    As[la_k + 1][la_r] = a4.y;
    As[la_k + 2][la_r] = a4.z;
    As[la_k + 3][la_r] = a4.w;
    *(float4*)&Bs[lb_k][lb_n] = b4;
    __syncthreads();
#pragma unroll
    for (int kk = 0; kk < 16; kk++) {
      float4 av = *(const float4*)&As[kk][ty * 4];
      float4 bv = *(const float4*)&Bs[kk][tx * 4];
      float a[4] = {av.x, av.y, av.z, av.w};
      float b[4] = {bv.x, bv.y, bv.z, bv.w};
#pragma unroll
      for (int i = 0; i < 4; i++)
#pragma unroll
        for (int j = 0; j < 4; j++) acc[i][j] = fmaf(a[i], b[j], acc[i][j]);
    }
  }
#pragma unroll
  for (int i = 0; i < 4; i++) {
    int r = row0 + ty * 4 + i;
#pragma unroll
    for (int j = 0; j < 4; j++) {
      int cc = col0 + tx * 4 + j;
      float v = acc[i][j];
      if (BIAS) v += bias[cc];
      if (RELU) v = fmaxf(v, 0.f);
      C[(size_t)r * N + cc] = v;
    }
  }
}

// n1[target[j]] += Htmp[src[j]] for edges in group (f,t); wave per edge
__global__ __launch_bounds__(256) void scatter_n1_kernel(
    const float* __restrict__ Htmp, const int* __restrict__ hete,
    const int* __restrict__ etype, const int* __restrict__ src,
    const int* __restrict__ target, float* __restrict__ n, int f, int t) {
  int j = blockIdx.x * 4 + (threadIdx.x >> 6);
  int lane = threadIdx.x & 63;
  int ef = (hete[j] > 0) ? 0 : 1;
  if (ef != f || etype[j] != t) return;
  const float* hp = Htmp + (size_t)src[j] * D_;
  float* np_ = n + (size_t)target[j] * D2_;
#pragma unroll
  for (int i = 0; i < 12; i++) {
    int k = lane + i * 64;
    atomicAdd(np_ + k, hp[k]);
  }
}

// n2[v] += cnt[v,t] * Htmp[v]   (Htmp already relu'd)
__global__ __launch_bounds__(256) void accum_n2_kernel(
    const float* __restrict__ Htmp, const int* __restrict__ cnt4,
    float* __restrict__ n, int t) {
  int v = blockIdx.y;
  int c = cnt4[v * 4 + t];
  if (c == 0) return;
  int k = blockIdx.x * 256 + threadIdx.x;
  n[(size_t)v * D2_ + D_ + k] += (float)c * Htmp[(size_t)v * D_ + k];
}

__global__ __launch_bounds__(256) void norm_kernel(
    const float* __restrict__ z, float* __restrict__ out) {
  int v = blockIdx.x, tid = threadIdx.x;
  const float* zr = z + (size_t)v * D_;
  float e0 = zr[tid], e1 = zr[tid + 256], e2 = zr[tid + 512];
  float q = e0 * e0 + e1 * e1 + e2 * e2;
  __shared__ float red[4];
  __shared__ float sc;
  float wq = wave_sum(q);
  int lane = tid & 63, w = tid >> 6;
  if (lane == 0) red[w] = wq;
  __syncthreads();
  if (tid == 0) {
    float S = red[0] + red[1] + red[2] + red[3];
    float norm = sqrtf(S);
    sc = (norm == 0.f) ? 1.f : (1.f / norm);
  }
  __syncthreads();
  float s = sc;
  float* orow = out + (size_t)v * D_;
  orow[tid]       = e0 * s;
  orow[tid + 256] = e1 * s;
  orow[tid + 512] = e2 * s;
}

extern "C" void kernel_launch(void* const* d_in, const int* in_sizes, int n_in,
                              void* d_out, int out_size, void* d_ws,
                              size_t ws_size, hipStream_t stream) {
  (void)in_sizes; (void)n_in; (void)out_size; (void)ws_size;
  const float* h      = (const float*)d_in[0];
  const float* W_text = (const float*)d_in[1];
  const float* c_text = (const float*)d_in[2];
  const float* W_user = (const float*)d_in[3];
  const float* c_user = (const float*)d_in[4];
  const float* W_dst  = (const float*)d_in[5];
  const float* c_dst  = (const float*)d_in[6];
  const float* gamma  = (const float*)d_in[7];
  const float* beta   = (const float*)d_in[8];
  const float* W_lin  = (const float*)d_in[9];
  const float* b_lin  = (const float*)d_in[10];
  const int* src      = (const int*)d_in[11];
  const int* dst      = (const int*)d_in[12];
  const int* etype    = (const int*)d_in[13];
  const int* hete     = (const int*)d_in[14];
  float* out          = (float*)d_out;

  char* ws = (char*)d_ws;
  float* x     = (float*)(ws + OFF_X);
  float* Wc    = (float*)(ws + OFF_WC);
  float* Htmp  = (float*)(ws + OFF_HT);
  float* nbuf  = (float*)(ws + OFF_N);
  int* target  = (int*)(ws + OFF_TG);
  int* cnt4    = (int*)(ws + OFF_CNT);
  int* blockcnt = (int*)(ws + OFF_BC);
  int* scanout  = (int*)(ws + OFF_SCAN);

  hipMemsetAsync(nbuf, 0, (size_t)N_ * D2_ * 4, stream);
  hipMemsetAsync(cnt4, 0, (size_t)N_ * 4 * 4, stream);

  combine_w_kernel<<<dim3(DSQ_ / 256, 12), 256, 0, stream>>>(
      W_text, c_text, W_user, c_user, W_dst, c_dst, Wc);
  ln_kernel<<<N_, 256, 0, stream>>>(h, gamma, beta, x);
  edge_a_kernel<<<E_ / 256, 256, 0, stream>>>(hete, dst, etype, blockcnt, cnt4);
  scan_kernel<<<1, 512, 0, stream>>>(blockcnt, scanout);
  edge_b_kernel<<<E_ / 256, 256, 0, stream>>>(hete, dst, scanout, target);

  // src-side families: f=0 text (hete), f=1 user (homo)
  for (int f = 0; f < 2; f++) {
    for (int t = 0; t < 4; t++) {
      gemm_kernel<true, false><<<dim3(D_ / 64, N_ / 64), 256, 0, stream>>>(
          x, Wc + (size_t)(f * 4 + t) * DSQ_, nullptr, Htmp, N_, D_, D_);
      scatter_n1_kernel<<<E_ / 4, 256, 0, stream>>>(Htmp, hete, etype, src,
                                                    target, nbuf, f, t);
    }
  }
  // dst family
  for (int t = 0; t < 4; t++) {
    gemm_kernel<true, false><<<dim3(D_ / 64, N_ / 64), 256, 0, stream>>>(
        x, Wc + (size_t)(8 + t) * DSQ_, nullptr, Htmp, N_, D_, D_);
    accum_n2_kernel<<<dim3(3, N_), 256, 0, stream>>>(Htmp, cnt4, nbuf, t);
  }
  // z = relu(n @ W_lin + b_lin) -> Htmp (reused)
  gemm_kernel<true, true><<<dim3(D_ / 64, N_ / 64), 256, 0, stream>>>(
      nbuf, W_lin, b_lin, Htmp, N_, D_, D2_);
  norm_kernel<<<N_, 256, 0, stream>>>(Htmp, out);
}

// Round 3
// 1067.825 us; speedup vs baseline: 3.8074x; 3.8074x over previous
//
#include <hip/hip_runtime.h>
#include <hip/hip_bf16.h>
#include <cstdint>

static constexpr int N_  = 16384;
static constexpr int E_  = 131072;
static constexpr int D_  = 768;
static constexpr int D2_ = 1536;
static constexpr int DSQ_ = D_ * D_;

// ---------------- workspace layout (bytes) ----------------
// x_bf16 [0, 25165824) ; WcT [25165824, 39321600)  -- both dead before f2b
// nbuf_bf16 reuses [0, 50331648)
static constexpr size_t OFF_XB   = 0;           // N*D bf16   = 25165824
static constexpr size_t OFF_WCT  = 25165824;    // 12*D*D bf16 = 14155776
static constexpr size_t OFF_NB16 = 0;           // N*2D bf16  = 50331648 (reuse)
static constexpr size_t OFF_HT   = 50331648;    // N*D fp32   = 50331648
static constexpr size_t OFF_WLT  = 100663296;   // D*2D bf16  = 2359296
static constexpr size_t OFF_N    = 103022592;   // N*2D fp32  = 100663296
static constexpr size_t OFF_TG   = 203685888;   // E int32
static constexpr size_t OFF_CNT  = 204210176;   // N*4 int32
static constexpr size_t OFF_BC   = 204472320;   // 512 int32
static constexpr size_t OFF_SCAN = 204474368;   // 513 int32

typedef __attribute__((ext_vector_type(8))) short short8v;
typedef __attribute__((ext_vector_type(4))) float floatx4;

__device__ __forceinline__ void gld16(const void* g, void* l) {
  __builtin_amdgcn_global_load_lds(
      (const __attribute__((address_space(1))) unsigned int*)g,
      (__attribute__((address_space(3))) unsigned int*)l, 16, 0, 0);
}

__device__ __forceinline__ float wave_sum(float v) {
#pragma unroll
  for (int o = 32; o; o >>= 1) v += __shfl_down(v, o, 64);
  return v;
}

// WcT[ft][h][d] = sum_b coeff_f[t,b] * W_f[b][d][h]  (bf16, transposed)
__global__ __launch_bounds__(256) void combine_wt_kernel(
    const float* __restrict__ Wt, const float* __restrict__ ct,
    const float* __restrict__ Wu, const float* __restrict__ cu,
    const float* __restrict__ Wd, const float* __restrict__ cd,
    __hip_bfloat16* __restrict__ WcT) {
  int i  = blockIdx.x * 256 + threadIdx.x;   // < D*D, i = d*768 + h (read-coalesced)
  int ft = blockIdx.y;                        // 0..11
  int f = ft >> 2, t = ft & 3;
  const float* W = (f == 0) ? Wt : ((f == 1) ? Wu : Wd);
  const float* c = ((f == 0) ? ct : ((f == 1) ? cu : cd)) + t * 3;
  float v = c[0] * W[i] + c[1] * W[DSQ_ + i] + c[2] * W[2 * DSQ_ + i];
  int d = i / D_, h = i % D_;
  WcT[(size_t)ft * DSQ_ + (size_t)h * D_ + d] = __float2bfloat16(v);
}

// W_linT[h][k] = W_lin[k][h] (bf16)
__global__ __launch_bounds__(256) void wlint_kernel(
    const float* __restrict__ W, __hip_bfloat16* __restrict__ WT) {
  int i = blockIdx.x * 256 + threadIdx.x;    // < 2D*D, i = k*768 + h
  int k = i / D_, h = i % D_;
  WT[(size_t)h * D2_ + k] = __float2bfloat16(W[i]);
}

__global__ __launch_bounds__(256) void ln_kernel(
    const float* __restrict__ h, const float* __restrict__ gamma,
    const float* __restrict__ beta, __hip_bfloat16* __restrict__ x) {
  int v = blockIdx.x, tid = threadIdx.x;
  const float* hr = h + (size_t)v * D_;
  float e0 = hr[tid], e1 = hr[tid + 256], e2 = hr[tid + 512];
  float s = e0 + e1 + e2;
  float q = e0 * e0 + e1 * e1 + e2 * e2;
  __shared__ float red[8];
  __shared__ float mv[2];
  float ws_ = wave_sum(s), wq = wave_sum(q);
  int lane = tid & 63, w = tid >> 6;
  if (lane == 0) { red[w] = ws_; red[4 + w] = wq; }
  __syncthreads();
  if (tid == 0) {
    float S = red[0] + red[1] + red[2] + red[3];
    float Q = red[4] + red[5] + red[6] + red[7];
    float mu = S * (1.0f / D_);
    float var = Q * (1.0f / D_) - mu * mu;
    mv[0] = mu;
    mv[1] = rsqrtf(var + 1e-5f);
  }
  __syncthreads();
  float mu = mv[0], rstd = mv[1];
  __hip_bfloat16* xr = x + (size_t)v * D_;
  xr[tid]       = __float2bfloat16((e0 - mu) * rstd * gamma[tid]       + beta[tid]);
  xr[tid + 256] = __float2bfloat16((e1 - mu) * rstd * gamma[tid + 256] + beta[tid + 256]);
  xr[tid + 512] = __float2bfloat16((e2 - mu) * rstd * gamma[tid + 512] + beta[tid + 512]);
}

// per-block hete counts + (dst,etype) histogram
__global__ __launch_bounds__(256) void edge_a_kernel(
    const int* __restrict__ hete, const int* __restrict__ dst,
    const int* __restrict__ etype, int* __restrict__ blockcnt,
    int* __restrict__ cnt4) {
  int j = blockIdx.x * 256 + threadIdx.x;
  int flag = hete[j] > 0;
  unsigned long long m = __ballot(flag);
  __shared__ int wsum[4];
  int lane = threadIdx.x & 63, w = threadIdx.x >> 6;
  if (lane == 0) wsum[w] = __popcll(m);
  __syncthreads();
  if (threadIdx.x == 0)
    blockcnt[blockIdx.x] = wsum[0] + wsum[1] + wsum[2] + wsum[3];
  atomicAdd(&cnt4[dst[j] * 4 + etype[j]], 1);
}

// single-block scan over 512 block counts -> exclusive offsets + total K
__global__ __launch_bounds__(512) void scan_kernel(
    const int* __restrict__ blockcnt, int* __restrict__ scanout) {
  __shared__ int s[512];
  int t = threadIdx.x;
  int v = blockcnt[t];
  s[t] = v;
  __syncthreads();
  for (int o = 1; o < 512; o <<= 1) {
    int add = (t >= o) ? s[t - o] : 0;
    __syncthreads();
    s[t] += add;
    __syncthreads();
  }
  scanout[t] = s[t] - v;             // exclusive prefix
  if (t == 511) scanout[512] = s[511];  // total hete count K
}

// target[j] = dst[perm_inv[j]]
__global__ __launch_bounds__(256) void edge_b_kernel(
    const int* __restrict__ hete, const int* __restrict__ dst,
    const int* __restrict__ scanout, int* __restrict__ target) {
  int j = blockIdx.x * 256 + threadIdx.x;
  int flag = hete[j] > 0;
  unsigned long long m = __ballot(flag);
  __shared__ int wsum[4];
  int lane = threadIdx.x & 63, w = threadIdx.x >> 6;
  if (lane == 0) wsum[w] = __popcll(m);
  __syncthreads();
  int wpre = 0;
#pragma unroll
  for (int i = 0; i < 4; i++) wpre += (i < w) ? wsum[i] : 0;
  int lpre = __popcll(m & ((1ull << lane) - 1ull));
  int hcum = scanout[blockIdx.x] + wpre + lpre;  // # hete edges with idx < j
  int K = scanout[512];
  int e = flag ? hcum : (K + j - hcum);
  target[j] = dst[e];
}

// C[M,N] = relu(A[M,K] @ BT[N,K]^T (+bias)), A/BT bf16, C fp32.
// 128x128 tile, BK=64, 4 waves (2x2), 16x16x32 bf16 MFMA, 4x4 frags/wave.
// LDS: linear fill via global_load_lds(16B); XOR swizzle (slot ^= row&7)
// applied on the GLOBAL source side (write) and on ds_read addresses (read).
template <bool BIAS>
__global__ __launch_bounds__(256) void gemm_mfma_kernel(
    const __hip_bfloat16* __restrict__ A, const __hip_bfloat16* __restrict__ BT,
    const float* __restrict__ bias, float* __restrict__ C,
    int M, int N, int K) {
  __shared__ char lds[32768];
  char* As = lds;
  char* Bs = lds + 16384;
  int tid = threadIdx.x;
  int lane = tid & 63;
  int wv = tid >> 6;
  int wr = wv >> 1, wc = wv & 1;           // 2x2 wave grid, wave tile 64x64
  int row0 = blockIdx.y * 128, col0 = blockIdx.x * 128;
  int r_ = tid >> 3;                        // staging row within 32-row group
  int s_ = tid & 7;                         // 16B slot within 128B row

  floatx4 acc[4][4];
#pragma unroll
  for (int i = 0; i < 4; i++)
#pragma unroll
    for (int j = 0; j < 4; j++) acc[i][j] = floatx4{0.f, 0.f, 0.f, 0.f};

  for (int k0 = 0; k0 < K; k0 += 64) {
    __syncthreads();
#pragma unroll
    for (int is = 0; is < 4; is++) {
      int r = is * 32 + r_;
      int sp = s_ ^ (r & 7);                // inverse swizzle on global source
      gld16(A  + (size_t)(row0 + r) * K + k0 + sp * 8, As + is * 4096 + tid * 16);
      gld16(BT + (size_t)(col0 + r) * K + k0 + sp * 8, Bs + is * 4096 + tid * 16);
    }
    __syncthreads();
#pragma unroll
    for (int kk = 0; kk < 64; kk += 32) {
      int p = (kk >> 3) + (lane >> 4);      // k-part index 0..7
      short8v af[4], bf[4];
#pragma unroll
      for (int m = 0; m < 4; m++) {
        int ra = wr * 64 + m * 16 + (lane & 15);
        af[m] = *(const short8v*)(As + ra * 128 + ((p ^ (ra & 7)) << 4));
        int rb = wc * 64 + m * 16 + (lane & 15);
        bf[m] = *(const short8v*)(Bs + rb * 128 + ((p ^ (rb & 7)) << 4));
      }
#pragma unroll
      for (int m = 0; m < 4; m++)
#pragma unroll
        for (int n = 0; n < 4; n++)
          acc[m][n] = __builtin_amdgcn_mfma_f32_16x16x32_bf16(
              af[m], bf[n], acc[m][n], 0, 0, 0);
    }
  }
  // epilogue: C/D layout col=lane&15, row=(lane>>4)*4+q
#pragma unroll
  for (int m = 0; m < 4; m++) {
#pragma unroll
    for (int n = 0; n < 4; n++) {
      int col = col0 + wc * 64 + n * 16 + (lane & 15);
      float bv = BIAS ? bias[col] : 0.f;
#pragma unroll
      for (int q = 0; q < 4; q++) {
        int row = row0 + wr * 64 + m * 16 + (lane >> 4) * 4 + q;
        float v = acc[m][n][q] + bv;
        v = fmaxf(v, 0.f);
        C[(size_t)row * N + col] = v;
      }
    }
  }
}

// n1[target[j]] += Htmp[src[j]] for edges in group (f,t); wave per edge
__global__ __launch_bounds__(256) void scatter_n1_kernel(
    const float* __restrict__ Htmp, const int* __restrict__ hete,
    const int* __restrict__ etype, const int* __restrict__ src,
    const int* __restrict__ target, float* __restrict__ n, int f, int t) {
  int j = blockIdx.x * 4 + (threadIdx.x >> 6);
  int lane = threadIdx.x & 63;
  int ef = (hete[j] > 0) ? 0 : 1;
  if (ef != f || etype[j] != t) return;
  const float* hp = Htmp + (size_t)src[j] * D_;
  float* np_ = n + (size_t)target[j] * D2_;
#pragma unroll
  for (int i = 0; i < 12; i++) {
    int k = lane + i * 64;
    atomicAdd(np_ + k, hp[k]);
  }
}

// n2[v] += cnt[v,t] * Htmp[v]   (Htmp already relu'd)
__global__ __launch_bounds__(256) void accum_n2_kernel(
    const float* __restrict__ Htmp, const int* __restrict__ cnt4,
    float* __restrict__ n, int t) {
  int v = blockIdx.y;
  int c = cnt4[v * 4 + t];
  if (c == 0) return;
  int k = blockIdx.x * 256 + threadIdx.x;
  n[(size_t)v * D2_ + D_ + k] += (float)c * Htmp[(size_t)v * D_ + k];
}

// fp32 -> bf16, 8 elems/thread
__global__ __launch_bounds__(256) void f2b_kernel(
    const float* __restrict__ in, __hip_bfloat16* __restrict__ out) {
  size_t i = ((size_t)blockIdx.x * 256 + threadIdx.x) * 8;
  float4 a = *(const float4*)(in + i);
  float4 b = *(const float4*)(in + i + 4);
  __hip_bfloat16 o[8] = {
      __float2bfloat16(a.x), __float2bfloat16(a.y), __float2bfloat16(a.z),
      __float2bfloat16(a.w), __float2bfloat16(b.x), __float2bfloat16(b.y),
      __float2bfloat16(b.z), __float2bfloat16(b.w)};
  *(short8v*)(out + i) = *(const short8v*)o;
}

__global__ __launch_bounds__(256) void norm_kernel(
    const float* __restrict__ z, float* __restrict__ out) {
  int v = blockIdx.x, tid = threadIdx.x;
  const float* zr = z + (size_t)v * D_;
  float e0 = zr[tid], e1 = zr[tid + 256], e2 = zr[tid + 512];
  float q = e0 * e0 + e1 * e1 + e2 * e2;
  __shared__ float red[4];
  __shared__ float sc;
  float wq = wave_sum(q);
  int lane = tid & 63, w = tid >> 6;
  if (lane == 0) red[w] = wq;
  __syncthreads();
  if (tid == 0) {
    float S = red[0] + red[1] + red[2] + red[3];
    float norm = sqrtf(S);
    sc = (norm == 0.f) ? 1.f : (1.f / norm);
  }
  __syncthreads();
  float s = sc;
  float* orow = out + (size_t)v * D_;
  orow[tid]       = e0 * s;
  orow[tid + 256] = e1 * s;
  orow[tid + 512] = e2 * s;
}

extern "C" void kernel_launch(void* const* d_in, const int* in_sizes, int n_in,
                              void* d_out, int out_size, void* d_ws,
                              size_t ws_size, hipStream_t stream) {
  (void)in_sizes; (void)n_in; (void)out_size; (void)ws_size;
  const float* h      = (const float*)d_in[0];
  const float* W_text = (const float*)d_in[1];
  const float* c_text = (const float*)d_in[2];
  const float* W_user = (const float*)d_in[3];
  const float* c_user = (const float*)d_in[4];
  const float* W_dst  = (const float*)d_in[5];
  const float* c_dst  = (const float*)d_in[6];
  const float* gamma  = (const float*)d_in[7];
  const float* beta   = (const float*)d_in[8];
  const float* W_lin  = (const float*)d_in[9];
  const float* b_lin  = (const float*)d_in[10];
  const int* src      = (const int*)d_in[11];
  const int* dst      = (const int*)d_in[12];
  const int* etype    = (const int*)d_in[13];
  const int* hete     = (const int*)d_in[14];
  float* out          = (float*)d_out;

  char* ws = (char*)d_ws;
  __hip_bfloat16* xb    = (__hip_bfloat16*)(ws + OFF_XB);
  __hip_bfloat16* WcT   = (__hip_bfloat16*)(ws + OFF_WCT);
  __hip_bfloat16* nb16  = (__hip_bfloat16*)(ws + OFF_NB16);
  float* Htmp           = (float*)(ws + OFF_HT);
  __hip_bfloat16* WlT   = (__hip_bfloat16*)(ws + OFF_WLT);
  float* nbuf           = (float*)(ws + OFF_N);
  int* target   = (int*)(ws + OFF_TG);
  int* cnt4     = (int*)(ws + OFF_CNT);
  int* blockcnt = (int*)(ws + OFF_BC);
  int* scanout  = (int*)(ws + OFF_SCAN);

  hipMemsetAsync(nbuf, 0, (size_t)N_ * D2_ * 4, stream);
  hipMemsetAsync(cnt4, 0, (size_t)N_ * 4 * 4, stream);

  combine_wt_kernel<<<dim3(DSQ_ / 256, 12), 256, 0, stream>>>(
      W_text, c_text, W_user, c_user, W_dst, c_dst, WcT);
  wlint_kernel<<<(D2_ * D_) / 256, 256, 0, stream>>>(W_lin, WlT);
  ln_kernel<<<N_, 256, 0, stream>>>(h, gamma, beta, xb);
  edge_a_kernel<<<E_ / 256, 256, 0, stream>>>(hete, dst, etype, blockcnt, cnt4);
  scan_kernel<<<1, 512, 0, stream>>>(blockcnt, scanout);
  edge_b_kernel<<<E_ / 256, 256, 0, stream>>>(hete, dst, scanout, target);

  // src-side families: f=0 text (hete), f=1 user (homo)
  for (int f = 0; f < 2; f++) {
    for (int t = 0; t < 4; t++) {
      gemm_mfma_kernel<false><<<dim3(D_ / 128, N_ / 128), 256, 0, stream>>>(
          xb, WcT + (size_t)(f * 4 + t) * DSQ_, nullptr, Htmp, N_, D_, D_);
      scatter_n1_kernel<<<E_ / 4, 256, 0, stream>>>(Htmp, hete, etype, src,
                                                    target, nbuf, f, t);
    }
  }
  // dst family
  for (int t = 0; t < 4; t++) {
    gemm_mfma_kernel<false><<<dim3(D_ / 128, N_ / 128), 256, 0, stream>>>(
        xb, WcT + (size_t)(8 + t) * DSQ_, nullptr, Htmp, N_, D_, D_);
    accum_n2_kernel<<<dim3(3, N_), 256, 0, stream>>>(Htmp, cnt4, nbuf, t);
  }
  // nbuf -> bf16, then z = relu(nbuf @ W_lin + b_lin) -> Htmp
  f2b_kernel<<<(N_ * D2_) / (256 * 8), 256, 0, stream>>>(nbuf, nb16);
  gemm_mfma_kernel<true><<<dim3(D_ / 128, N_ / 128), 256, 0, stream>>>(
      nb16, WlT, b_lin, Htmp, N_, D_, D2_);
  norm_kernel<<<N_, 256, 0, stream>>>(Htmp, out);
}

// Round 4
// 1004.998 us; speedup vs baseline: 4.0454x; 1.0625x over previous
//
#include <hip/hip_runtime.h>
#include <hip/hip_bf16.h>
#include <cstdint>

static constexpr int N_  = 16384;
static constexpr int E_  = 131072;
static constexpr int D_  = 768;
static constexpr int D2_ = 1536;
static constexpr int DSQ_ = D_ * D_;

// ---------------- workspace layout (bytes) ----------------
// typed phase: xb [0,25.2M), WcT [25.2M,39.3M)
// f2b phase:   nb16 [0,50.3M) overwrites xb+WcT (both dead)
// Htmp: bf16 (25.2M) during typed phase; z fp32 (50.3M) for final GEMM
static constexpr size_t OFF_XB   = 0;           // N*D bf16   = 25165824
static constexpr size_t OFF_WCT  = 25165824;    // 12*D*D bf16 = 14155776
static constexpr size_t OFF_NB16 = 0;           // N*2D bf16  = 50331648 (reuse)
static constexpr size_t OFF_HT   = 50331648;    // N*D fp32 / N*D bf16
static constexpr size_t OFF_WLT  = 100663296;   // D*2D bf16  = 2359296
static constexpr size_t OFF_N    = 103022592;   // N*2D fp32  = 100663296
static constexpr size_t OFF_TG   = 203685888;   // E int32
static constexpr size_t OFF_CNT  = 204210176;   // N*4 int32
static constexpr size_t OFF_BC   = 204472320;   // 512 int32
static constexpr size_t OFF_SCAN = 204474368;   // 513 int32

typedef __attribute__((ext_vector_type(8))) short short8v;
typedef __attribute__((ext_vector_type(4))) float floatx4;

__device__ __forceinline__ void gld16(const void* g, void* l) {
  __builtin_amdgcn_global_load_lds(
      (const __attribute__((address_space(1))) unsigned int*)g,
      (__attribute__((address_space(3))) unsigned int*)l, 16, 0, 0);
}

__device__ __forceinline__ float wave_sum(float v) {
#pragma unroll
  for (int o = 32; o; o >>= 1) v += __shfl_down(v, o, 64);
  return v;
}

// WcT[ft][h][d] = sum_b coeff_f[t,b] * W_f[b][d][h]  (bf16, transposed)
__global__ __launch_bounds__(256) void combine_wt_kernel(
    const float* __restrict__ Wt, const float* __restrict__ ct,
    const float* __restrict__ Wu, const float* __restrict__ cu,
    const float* __restrict__ Wd, const float* __restrict__ cd,
    __hip_bfloat16* __restrict__ WcT) {
  int i  = blockIdx.x * 256 + threadIdx.x;   // < D*D, i = d*768 + h (read-coalesced)
  int ft = blockIdx.y;                        // 0..11
  int f = ft >> 2, t = ft & 3;
  const float* W = (f == 0) ? Wt : ((f == 1) ? Wu : Wd);
  const float* c = ((f == 0) ? ct : ((f == 1) ? cu : cd)) + t * 3;
  float v = c[0] * W[i] + c[1] * W[DSQ_ + i] + c[2] * W[2 * DSQ_ + i];
  int d = i / D_, h = i % D_;
  WcT[(size_t)ft * DSQ_ + (size_t)h * D_ + d] = __float2bfloat16(v);
}

// W_linT[h][k] = W_lin[k][h] (bf16)
__global__ __launch_bounds__(256) void wlint_kernel(
    const float* __restrict__ W, __hip_bfloat16* __restrict__ WT) {
  int i = blockIdx.x * 256 + threadIdx.x;    // < 2D*D, i = k*768 + h
  int k = i / D_, h = i % D_;
  WT[(size_t)h * D2_ + k] = __float2bfloat16(W[i]);
}

__global__ __launch_bounds__(256) void ln_kernel(
    const float* __restrict__ h, const float* __restrict__ gamma,
    const float* __restrict__ beta, __hip_bfloat16* __restrict__ x) {
  int v = blockIdx.x, tid = threadIdx.x;
  const float* hr = h + (size_t)v * D_;
  float e0 = hr[tid], e1 = hr[tid + 256], e2 = hr[tid + 512];
  float s = e0 + e1 + e2;
  float q = e0 * e0 + e1 * e1 + e2 * e2;
  __shared__ float red[8];
  __shared__ float mv[2];
  float ws_ = wave_sum(s), wq = wave_sum(q);
  int lane = tid & 63, w = tid >> 6;
  if (lane == 0) { red[w] = ws_; red[4 + w] = wq; }
  __syncthreads();
  if (tid == 0) {
    float S = red[0] + red[1] + red[2] + red[3];
    float Q = red[4] + red[5] + red[6] + red[7];
    float mu = S * (1.0f / D_);
    float var = Q * (1.0f / D_) - mu * mu;
    mv[0] = mu;
    mv[1] = rsqrtf(var + 1e-5f);
  }
  __syncthreads();
  float mu = mv[0], rstd = mv[1];
  __hip_bfloat16* xr = x + (size_t)v * D_;
  xr[tid]       = __float2bfloat16((e0 - mu) * rstd * gamma[tid]       + beta[tid]);
  xr[tid + 256] = __float2bfloat16((e1 - mu) * rstd * gamma[tid + 256] + beta[tid + 256]);
  xr[tid + 512] = __float2bfloat16((e2 - mu) * rstd * gamma[tid + 512] + beta[tid + 512]);
}

// per-block hete counts + (dst,etype) histogram
__global__ __launch_bounds__(256) void edge_a_kernel(
    const int* __restrict__ hete, const int* __restrict__ dst,
    const int* __restrict__ etype, int* __restrict__ blockcnt,
    int* __restrict__ cnt4) {
  int j = blockIdx.x * 256 + threadIdx.x;
  int flag = hete[j] > 0;
  unsigned long long m = __ballot(flag);
  __shared__ int wsum[4];
  int lane = threadIdx.x & 63, w = threadIdx.x >> 6;
  if (lane == 0) wsum[w] = __popcll(m);
  __syncthreads();
  if (threadIdx.x == 0)
    blockcnt[blockIdx.x] = wsum[0] + wsum[1] + wsum[2] + wsum[3];
  atomicAdd(&cnt4[dst[j] * 4 + etype[j]], 1);
}

// single-block scan over 512 block counts -> exclusive offsets + total K
__global__ __launch_bounds__(512) void scan_kernel(
    const int* __restrict__ blockcnt, int* __restrict__ scanout) {
  __shared__ int s[512];
  int t = threadIdx.x;
  int v = blockcnt[t];
  s[t] = v;
  __syncthreads();
  for (int o = 1; o < 512; o <<= 1) {
    int add = (t >= o) ? s[t - o] : 0;
    __syncthreads();
    s[t] += add;
    __syncthreads();
  }
  scanout[t] = s[t] - v;             // exclusive prefix
  if (t == 511) scanout[512] = s[511];  // total hete count K
}

// target[j] = dst[perm_inv[j]]
__global__ __launch_bounds__(256) void edge_b_kernel(
    const int* __restrict__ hete, const int* __restrict__ dst,
    const int* __restrict__ scanout, int* __restrict__ target) {
  int j = blockIdx.x * 256 + threadIdx.x;
  int flag = hete[j] > 0;
  unsigned long long m = __ballot(flag);
  __shared__ int wsum[4];
  int lane = threadIdx.x & 63, w = threadIdx.x >> 6;
  if (lane == 0) wsum[w] = __popcll(m);
  __syncthreads();
  int wpre = 0;
#pragma unroll
  for (int i = 0; i < 4; i++) wpre += (i < w) ? wsum[i] : 0;
  int lpre = __popcll(m & ((1ull << lane) - 1ull));
  int hcum = scanout[blockIdx.x] + wpre + lpre;  // # hete edges with idx < j
  int K = scanout[512];
  int e = flag ? hcum : (K + j - hcum);
  target[j] = dst[e];
}

// C[M,N] = relu(A[M,K] @ BT[N,K]^T (+bias)), A/BT bf16, C bf16 or fp32.
// 128x128 tile, BK=64, 4 waves (2x2), 16x16x32 bf16 MFMA, 4x4 frags/wave.
// LDS: linear fill via global_load_lds(16B); XOR swizzle (slot ^= row&7)
// applied on the GLOBAL source side (write) and on ds_read addresses (read).
// XCD-chunked block swizzle: XCD k owns 96 consecutive (by-major) blocks ->
// 16 A-panels (3.1 MB) stay L2-resident, swept over all 6 col-blocks.
template <bool BIAS, bool OUTBF16>
__global__ __launch_bounds__(256) void gemm_mfma_kernel(
    const __hip_bfloat16* __restrict__ A, const __hip_bfloat16* __restrict__ BT,
    const float* __restrict__ bias, void* __restrict__ Cv,
    int M, int N, int K) {
  __shared__ char lds[32768];
  char* As = lds;
  char* Bs = lds + 16384;
  int tid = threadIdx.x;
  int lane = tid & 63;
  int wv = tid >> 6;
  int wr = wv >> 1, wc = wv & 1;           // 2x2 wave grid, wave tile 64x64
  // XCD swizzle (nwg % 8 == 0 for all our shapes)
  int nwg = gridDim.x * gridDim.y;
  int id = blockIdx.y * gridDim.x + blockIdx.x;
  int s = (id & 7) * (nwg >> 3) + (id >> 3);
  int bx = s % gridDim.x, by = s / gridDim.x;
  int row0 = by * 128, col0 = bx * 128;
  int r_ = tid >> 3;                        // staging row within 32-row group
  int s_ = tid & 7;                         // 16B slot within 128B row

  floatx4 acc[4][4];
#pragma unroll
  for (int i = 0; i < 4; i++)
#pragma unroll
    for (int j = 0; j < 4; j++) acc[i][j] = floatx4{0.f, 0.f, 0.f, 0.f};

  for (int k0 = 0; k0 < K; k0 += 64) {
    __syncthreads();
#pragma unroll
    for (int is = 0; is < 4; is++) {
      int r = is * 32 + r_;
      int sp = s_ ^ (r & 7);                // inverse swizzle on global source
      gld16(A  + (size_t)(row0 + r) * K + k0 + sp * 8, As + is * 4096 + tid * 16);
      gld16(BT + (size_t)(col0 + r) * K + k0 + sp * 8, Bs + is * 4096 + tid * 16);
    }
    __syncthreads();
#pragma unroll
    for (int kk = 0; kk < 64; kk += 32) {
      int p = (kk >> 3) + (lane >> 4);      // k-part index 0..7
      short8v af[4], bf[4];
#pragma unroll
      for (int m = 0; m < 4; m++) {
        int ra = wr * 64 + m * 16 + (lane & 15);
        af[m] = *(const short8v*)(As + ra * 128 + ((p ^ (ra & 7)) << 4));
        int rb = wc * 64 + m * 16 + (lane & 15);
        bf[m] = *(const short8v*)(Bs + rb * 128 + ((p ^ (rb & 7)) << 4));
      }
#pragma unroll
      for (int m = 0; m < 4; m++)
#pragma unroll
        for (int n = 0; n < 4; n++)
          acc[m][n] = __builtin_amdgcn_mfma_f32_16x16x32_bf16(
              af[m], bf[n], acc[m][n], 0, 0, 0);
    }
  }
  // epilogue: C/D layout col=lane&15, row=(lane>>4)*4+q
#pragma unroll
  for (int m = 0; m < 4; m++) {
#pragma unroll
    for (int n = 0; n < 4; n++) {
      int col = col0 + wc * 64 + n * 16 + (lane & 15);
      float bv = BIAS ? bias[col] : 0.f;
#pragma unroll
      for (int q = 0; q < 4; q++) {
        int row = row0 + wr * 64 + m * 16 + (lane >> 4) * 4 + q;
        float v = fmaxf(acc[m][n][q] + bv, 0.f);
        if constexpr (OUTBF16) {
          ((__hip_bfloat16*)Cv)[(size_t)row * N + col] = __float2bfloat16(v);
        } else {
          ((float*)Cv)[(size_t)row * N + col] = v;
        }
      }
    }
  }
}

// n1[target[j]] += H[src[j]] for edges in group (f,t); wave per 4 edges
__global__ __launch_bounds__(256) void scatter_n1_kernel(
    const __hip_bfloat16* __restrict__ H, const int* __restrict__ hete,
    const int* __restrict__ etype, const int* __restrict__ src,
    const int* __restrict__ target, float* __restrict__ n, int f, int t) {
  int w = blockIdx.x * 4 + (threadIdx.x >> 6);
  int lane = threadIdx.x & 63;
#pragma unroll
  for (int u = 0; u < 4; u++) {
    int j = w * 4 + u;
    int ef = (hete[j] > 0) ? 0 : 1;
    if (ef != f || etype[j] != t) continue;
    const __hip_bfloat16* hp = H + (size_t)src[j] * D_;
    float* np_ = n + (size_t)target[j] * D2_;
#pragma unroll
    for (int i = 0; i < 12; i++) {
      int k = lane + i * 64;
      atomicAdd(np_ + k, __bfloat162float(hp[k]));
    }
  }
}

// n2[v] += cnt[v,t] * H[v]   (H already relu'd, bf16)
__global__ __launch_bounds__(256) void accum_n2_kernel(
    const __hip_bfloat16* __restrict__ H, const int* __restrict__ cnt4,
    float* __restrict__ n, int t) {
  int v = blockIdx.y;
  int c = cnt4[v * 4 + t];
  if (c == 0) return;
  int k = blockIdx.x * 256 + threadIdx.x;
  n[(size_t)v * D2_ + D_ + k] += (float)c * __bfloat162float(H[(size_t)v * D_ + k]);
}

// fp32 -> bf16, 8 elems/thread
__global__ __launch_bounds__(256) void f2b_kernel(
    const float* __restrict__ in, __hip_bfloat16* __restrict__ out) {
  size_t i = ((size_t)blockIdx.x * 256 + threadIdx.x) * 8;
  float4 a = *(const float4*)(in + i);
  float4 b = *(const float4*)(in + i + 4);
  __hip_bfloat16 o[8] = {
      __float2bfloat16(a.x), __float2bfloat16(a.y), __float2bfloat16(a.z),
      __float2bfloat16(a.w), __float2bfloat16(b.x), __float2bfloat16(b.y),
      __float2bfloat16(b.z), __float2bfloat16(b.w)};
  *(short8v*)(out + i) = *(const short8v*)o;
}

__global__ __launch_bounds__(256) void norm_kernel(
    const float* __restrict__ z, float* __restrict__ out) {
  int v = blockIdx.x, tid = threadIdx.x;
  const float* zr = z + (size_t)v * D_;
  float e0 = zr[tid], e1 = zr[tid + 256], e2 = zr[tid + 512];
  float q = e0 * e0 + e1 * e1 + e2 * e2;
  __shared__ float red[4];
  __shared__ float sc;
  float wq = wave_sum(q);
  int lane = tid & 63, w = tid >> 6;
  if (lane == 0) red[w] = wq;
  __syncthreads();
  if (tid == 0) {
    float S = red[0] + red[1] + red[2] + red[3];
    float norm = sqrtf(S);
    sc = (norm == 0.f) ? 1.f : (1.f / norm);
  }
  __syncthreads();
  float s = sc;
  float* orow = out + (size_t)v * D_;
  orow[tid]       = e0 * s;
  orow[tid + 256] = e1 * s;
  orow[tid + 512] = e2 * s;
}

extern "C" void kernel_launch(void* const* d_in, const int* in_sizes, int n_in,
                              void* d_out, int out_size, void* d_ws,
                              size_t ws_size, hipStream_t stream) {
  (void)in_sizes; (void)n_in; (void)out_size; (void)ws_size;
  const float* h      = (const float*)d_in[0];
  const float* W_text = (const float*)d_in[1];
  const float* c_text = (const float*)d_in[2];
  const float* W_user = (const float*)d_in[3];
  const float* c_user = (const float*)d_in[4];
  const float* W_dst  = (const float*)d_in[5];
  const float* c_dst  = (const float*)d_in[6];
  const float* gamma  = (const float*)d_in[7];
  const float* beta   = (const float*)d_in[8];
  const float* W_lin  = (const float*)d_in[9];
  const float* b_lin  = (const float*)d_in[10];
  const int* src      = (const int*)d_in[11];
  const int* dst      = (const int*)d_in[12];
  const int* etype    = (const int*)d_in[13];
  const int* hete     = (const int*)d_in[14];
  float* out          = (float*)d_out;

  char* ws = (char*)d_ws;
  __hip_bfloat16* xb    = (__hip_bfloat16*)(ws + OFF_XB);
  __hip_bfloat16* WcT   = (__hip_bfloat16*)(ws + OFF_WCT);
  __hip_bfloat16* nb16  = (__hip_bfloat16*)(ws + OFF_NB16);
  __hip_bfloat16* Hb    = (__hip_bfloat16*)(ws + OFF_HT);  // typed-phase H (bf16)
  float* zbuf           = (float*)(ws + OFF_HT);            // final z (fp32)
  __hip_bfloat16* WlT   = (__hip_bfloat16*)(ws + OFF_WLT);
  float* nbuf           = (float*)(ws + OFF_N);
  int* target   = (int*)(ws + OFF_TG);
  int* cnt4     = (int*)(ws + OFF_CNT);
  int* blockcnt = (int*)(ws + OFF_BC);
  int* scanout  = (int*)(ws + OFF_SCAN);

  hipMemsetAsync(nbuf, 0, (size_t)N_ * D2_ * 4, stream);
  hipMemsetAsync(cnt4, 0, (size_t)N_ * 4 * 4, stream);

  combine_wt_kernel<<<dim3(DSQ_ / 256, 12), 256, 0, stream>>>(
      W_text, c_text, W_user, c_user, W_dst, c_dst, WcT);
  wlint_kernel<<<(D2_ * D_) / 256, 256, 0, stream>>>(W_lin, WlT);
  ln_kernel<<<N_, 256, 0, stream>>>(h, gamma, beta, xb);
  edge_a_kernel<<<E_ / 256, 256, 0, stream>>>(hete, dst, etype, blockcnt, cnt4);
  scan_kernel<<<1, 512, 0, stream>>>(blockcnt, scanout);
  edge_b_kernel<<<E_ / 256, 256, 0, stream>>>(hete, dst, scanout, target);

  // src-side families: f=0 text (hete), f=1 user (homo)
  for (int f = 0; f < 2; f++) {
    for (int t = 0; t < 4; t++) {
      gemm_mfma_kernel<false, true><<<dim3(D_ / 128, N_ / 128), 256, 0, stream>>>(
          xb, WcT + (size_t)(f * 4 + t) * DSQ_, nullptr, Hb, N_, D_, D_);
      scatter_n1_kernel<<<E_ / 16, 256, 0, stream>>>(Hb, hete, etype, src,
                                                     target, nbuf, f, t);
    }
  }
  // dst family
  for (int t = 0; t < 4; t++) {
    gemm_mfma_kernel<false, true><<<dim3(D_ / 128, N_ / 128), 256, 0, stream>>>(
        xb, WcT + (size_t)(8 + t) * DSQ_, nullptr, Hb, N_, D_, D_);
    accum_n2_kernel<<<dim3(3, N_), 256, 0, stream>>>(Hb, cnt4, nbuf, t);
  }
  // nbuf -> bf16 (overwrites xb/WcT region, both dead), then final GEMM
  f2b_kernel<<<(N_ * D2_) / (256 * 8), 256, 0, stream>>>(nbuf, nb16);
  gemm_mfma_kernel<true, false><<<dim3(D_ / 128, N_ / 128), 256, 0, stream>>>(
      nb16, WlT, b_lin, zbuf, N_, D_, D2_);
  norm_kernel<<<N_, 256, 0, stream>>>(zbuf, out);
}

// Round 6
// 612.100 us; speedup vs baseline: 6.6421x; 1.6419x over previous
//
#include <hip/hip_runtime.h>
#include <hip/hip_bf16.h>
#include <cstdint>

static constexpr int N_  = 16384;
static constexpr int E_  = 131072;
static constexpr int D_  = 768;
static constexpr int D2_ = 1536;
static constexpr int DSQ_ = D_ * D_;

// ---------------- workspace layout (bytes), total ~219.3 MB ----------------
static constexpr size_t OFF_XB   = 0;            // N*D bf16    = 25165824
static constexpr size_t OFF_WCT  = 25165824;     // 12*D*D bf16 = 14155776
static constexpr size_t OFF_WLT  = 39321600;     // D*2D bf16   = 2359296
static constexpr size_t OFF_NB16 = 41680896;     // N*2D bf16   = 50331648
static constexpr size_t OFF_H3   = 92012544;     // 3 * N*D bf16 = 75497472
static constexpr size_t OFF_ZB   = 92012544;     // N*D fp32 (reuses H3 after gathers)
static constexpr size_t OFF_N1F  = 167510016;    // N*D fp32    = 50331648
static constexpr size_t OFF_TG   = 217841664;    // E int32     = 524288
static constexpr size_t OFF_PAY  = 218365952;    // E int32     = 524288
static constexpr size_t OFF_CNT  = 218890240;    // N*4 int32   = 262144
static constexpr size_t OFF_BASE = 219152384;    // (N+1) int32 = 65540 (pad to 65552)
static constexpr size_t OFF_CUR  = 219217936;    // N int32     = 65536
static constexpr size_t OFF_BC   = 219283472;    // 512 int32
static constexpr size_t OFF_SCAN = 219285520;    // 513 int32

typedef __attribute__((ext_vector_type(8))) short short8v;
typedef __attribute__((ext_vector_type(4))) float floatx4;

__device__ __forceinline__ void gld16(const void* g, void* l) {
  __builtin_amdgcn_global_load_lds(
      (const __attribute__((address_space(1))) unsigned int*)g,
      (__attribute__((address_space(3))) unsigned int*)l, 16, 0, 0);
}

__device__ __forceinline__ float wave_sum(float v) {
#pragma unroll
  for (int o = 32; o; o >>= 1) v += __shfl_down(v, o, 64);
  return v;
}

// WcT[ft][h][d] = sum_b coeff_f[t,b] * W_f[b][d][h]  (bf16, transposed)
__global__ __launch_bounds__(256) void combine_wt_kernel(
    const float* __restrict__ Wt, const float* __restrict__ ct,
    const float* __restrict__ Wu, const float* __restrict__ cu,
    const float* __restrict__ Wd, const float* __restrict__ cd,
    __hip_bfloat16* __restrict__ WcT) {
  int i  = blockIdx.x * 256 + threadIdx.x;   // < D*D, i = d*768 + h
  int ft = blockIdx.y;                        // 0..11
  int f = ft >> 2, t = ft & 3;
  const float* W = (f == 0) ? Wt : ((f == 1) ? Wu : Wd);
  const float* c = ((f == 0) ? ct : ((f == 1) ? cu : cd)) + t * 3;
  float v = c[0] * W[i] + c[1] * W[DSQ_ + i] + c[2] * W[2 * DSQ_ + i];
  int d = i / D_, h = i % D_;
  WcT[(size_t)ft * DSQ_ + (size_t)h * D_ + d] = __float2bfloat16(v);
}

// W_linT[h][k] = W_lin[k][h] (bf16)
__global__ __launch_bounds__(256) void wlint_kernel(
    const float* __restrict__ W, __hip_bfloat16* __restrict__ WT) {
  int i = blockIdx.x * 256 + threadIdx.x;    // < 2D*D, i = k*768 + h
  int k = i / D_, h = i % D_;
  WT[(size_t)h * D2_ + k] = __float2bfloat16(W[i]);
}

__global__ __launch_bounds__(256) void ln_kernel(
    const float* __restrict__ h, const float* __restrict__ gamma,
    const float* __restrict__ beta, __hip_bfloat16* __restrict__ x) {
  int v = blockIdx.x, tid = threadIdx.x;
  const float* hr = h + (size_t)v * D_;
  float e0 = hr[tid], e1 = hr[tid + 256], e2 = hr[tid + 512];
  float s = e0 + e1 + e2;
  float q = e0 * e0 + e1 * e1 + e2 * e2;
  __shared__ float red[8];
  __shared__ float mv[2];
  float ws_ = wave_sum(s), wq = wave_sum(q);
  int lane = tid & 63, w = tid >> 6;
  if (lane == 0) { red[w] = ws_; red[4 + w] = wq; }
  __syncthreads();
  if (tid == 0) {
    float S = red[0] + red[1] + red[2] + red[3];
    float Q = red[4] + red[5] + red[6] + red[7];
    float mu = S * (1.0f / D_);
    float var = Q * (1.0f / D_) - mu * mu;
    mv[0] = mu;
    mv[1] = rsqrtf(var + 1e-5f);
  }
  __syncthreads();
  float mu = mv[0], rstd = mv[1];
  __hip_bfloat16* xr = x + (size_t)v * D_;
  xr[tid]       = __float2bfloat16((e0 - mu) * rstd * gamma[tid]       + beta[tid]);
  xr[tid + 256] = __float2bfloat16((e1 - mu) * rstd * gamma[tid + 256] + beta[tid + 256]);
  xr[tid + 512] = __float2bfloat16((e2 - mu) * rstd * gamma[tid + 512] + beta[tid + 512]);
}

// per-block hete counts + (dst,etype) histogram
__global__ __launch_bounds__(256) void edge_a_kernel(
    const int* __restrict__ hete, const int* __restrict__ dst,
    const int* __restrict__ etype, int* __restrict__ blockcnt,
    int* __restrict__ cnt4) {
  int j = blockIdx.x * 256 + threadIdx.x;
  int flag = hete[j] > 0;
  unsigned long long m = __ballot(flag);
  __shared__ int wsum[4];
  int lane = threadIdx.x & 63, w = threadIdx.x >> 6;
  if (lane == 0) wsum[w] = __popcll(m);
  __syncthreads();
  if (threadIdx.x == 0)
    blockcnt[blockIdx.x] = wsum[0] + wsum[1] + wsum[2] + wsum[3];
  atomicAdd(&cnt4[dst[j] * 4 + etype[j]], 1);
}

// single-block scan over 512 block counts -> exclusive offsets + total K
__global__ __launch_bounds__(512) void scan_kernel(
    const int* __restrict__ blockcnt, int* __restrict__ scanout) {
  __shared__ int s[512];
  int t = threadIdx.x;
  int v = blockcnt[t];
  s[t] = v;
  __syncthreads();
  for (int o = 1; o < 512; o <<= 1) {
    int add = (t >= o) ? s[t - o] : 0;
    __syncthreads();
    s[t] += add;
    __syncthreads();
  }
  scanout[t] = s[t] - v;             // exclusive prefix
  if (t == 511) scanout[512] = s[511];  // total hete count K
}

// target[j] = dst[perm_inv[j]]
__global__ __launch_bounds__(256) void edge_b_kernel(
    const int* __restrict__ hete, const int* __restrict__ dst,
    const int* __restrict__ scanout, int* __restrict__ target) {
  int j = blockIdx.x * 256 + threadIdx.x;
  int flag = hete[j] > 0;
  unsigned long long m = __ballot(flag);
  __shared__ int wsum[4];
  int lane = threadIdx.x & 63, w = threadIdx.x >> 6;
  if (lane == 0) wsum[w] = __popcll(m);
  __syncthreads();
  int wpre = 0;
#pragma unroll
  for (int i = 0; i < 4; i++) wpre += (i < w) ? wsum[i] : 0;
  int lpre = __popcll(m & ((1ull << lane) - 1ull));
  int hcum = scanout[blockIdx.x] + wpre + lpre;  // # hete edges with idx < j
  int K = scanout[512];
  int e = flag ? hcum : (K + j - hcum);
  target[j] = dst[e];
}

// base[v] = exclusive prefix of deg[v] = sum_t cnt4[v,t]; base[N]=E
__global__ __launch_bounds__(1024) void base_scan_kernel(
    const int* __restrict__ cnt4, int* __restrict__ base) {
  __shared__ int s[1024];
  int t = threadIdx.x;
  int loc[16];
  int sum = 0;
#pragma unroll
  for (int i = 0; i < 16; i++) {
    int v = t * 16 + i;
    int d = cnt4[v * 4] + cnt4[v * 4 + 1] + cnt4[v * 4 + 2] + cnt4[v * 4 + 3];
    loc[i] = sum;
    sum += d;
  }
  s[t] = sum;
  __syncthreads();
  for (int o = 1; o < 1024; o <<= 1) {
    int add = (t >= o) ? s[t - o] : 0;
    __syncthreads();
    s[t] += add;
    __syncthreads();
  }
  int pre = t ? s[t - 1] : 0;
#pragma unroll
  for (int i = 0; i < 16; i++) base[t * 16 + i] = pre + loc[i];
  if (t == 1023) base[N_] = s[1023];
}

// payload[base[target[j]] + cursor++] = g<<14 | src[j]
__global__ __launch_bounds__(256) void edge_sort_kernel(
    const int* __restrict__ target, const int* __restrict__ src,
    const int* __restrict__ etype, const int* __restrict__ hete,
    const int* __restrict__ base, int* __restrict__ cursor,
    int* __restrict__ payload) {
  int j = blockIdx.x * 256 + threadIdx.x;
  int v = target[j];
  int p = base[v] + atomicAdd(&cursor[v], 1);
  int g = ((hete[j] > 0) ? 0 : 4) + etype[j];
  payload[p] = (g << 14) | src[j];
}

// one wave per node: acc over incoming edges whose group is in [g0, g0+gn)
template <bool FIRST, bool LAST>
__global__ __launch_bounds__(256) void gather_n1_kernel(
    const __hip_bfloat16* __restrict__ H, const int* __restrict__ base,
    const int* __restrict__ payload, float* __restrict__ n1f,
    __hip_bfloat16* __restrict__ nb16, int g0, int gn) {
  int wv = threadIdx.x >> 6, lane = threadIdx.x & 63;
  int v = blockIdx.x * 4 + wv;
  int b0 = base[v], b1 = base[v + 1];
  float acc[12];
#pragma unroll
  for (int i = 0; i < 12; i++)
    acc[i] = FIRST ? 0.f : n1f[(size_t)v * D_ + lane + i * 64];
  for (int idx = b0; idx < b1; ++idx) {
    int pl = payload[idx];
    int g = pl >> 14;
    if (g < g0 || g >= g0 + gn) continue;
    const __hip_bfloat16* row = H + ((size_t)(g - g0) * N_ + (pl & 16383)) * D_;
#pragma unroll
    for (int i = 0; i < 12; i++) acc[i] += __bfloat162float(row[lane + i * 64]);
  }
  if (LAST) {
#pragma unroll
    for (int i = 0; i < 12; i++)
      nb16[(size_t)v * D2_ + lane + i * 64] = __float2bfloat16(acc[i]);
  } else {
#pragma unroll
    for (int i = 0; i < 12; i++) n1f[(size_t)v * D_ + lane + i * 64] = acc[i];
  }
}

// C[M,N] = relu(A[M,K] @ BT[N,K]^T (+bias)), A/BT bf16, C bf16 or fp32.
// 128x128 tile, BK=64, 4 waves (2x2), 16x16x32 bf16 MFMA, XOR-swizzled LDS,
// XCD-chunked block swizzle.
template <bool BIAS, bool OUTBF16>
__global__ __launch_bounds__(256) void gemm_mfma_kernel(
    const __hip_bfloat16* __restrict__ A, const __hip_bfloat16* __restrict__ BT,
    const float* __restrict__ bias, void* __restrict__ Cv,
    int M, int N, int K) {
  __shared__ char lds[32768];
  char* As = lds;
  char* Bs = lds + 16384;
  int tid = threadIdx.x;
  int lane = tid & 63;
  int wv = tid >> 6;
  int wr = wv >> 1, wc = wv & 1;
  int nwg = gridDim.x * gridDim.y;
  int id = blockIdx.y * gridDim.x + blockIdx.x;
  int s = (id & 7) * (nwg >> 3) + (id >> 3);
  int bx = s % gridDim.x, by = s / gridDim.x;
  int row0 = by * 128, col0 = bx * 128;
  int r_ = tid >> 3;
  int s_ = tid & 7;

  floatx4 acc[4][4];
#pragma unroll
  for (int i = 0; i < 4; i++)
#pragma unroll
    for (int j = 0; j < 4; j++) acc[i][j] = floatx4{0.f, 0.f, 0.f, 0.f};

  for (int k0 = 0; k0 < K; k0 += 64) {
    __syncthreads();
#pragma unroll
    for (int is = 0; is < 4; is++) {
      int r = is * 32 + r_;
      int sp = s_ ^ (r & 7);
      gld16(A  + (size_t)(row0 + r) * K + k0 + sp * 8, As + is * 4096 + tid * 16);
      gld16(BT + (size_t)(col0 + r) * K + k0 + sp * 8, Bs + is * 4096 + tid * 16);
    }
    __syncthreads();
#pragma unroll
    for (int kk = 0; kk < 64; kk += 32) {
      int p = (kk >> 3) + (lane >> 4);
      short8v af[4], bf[4];
#pragma unroll
      for (int m = 0; m < 4; m++) {
        int ra = wr * 64 + m * 16 + (lane & 15);
        af[m] = *(const short8v*)(As + ra * 128 + ((p ^ (ra & 7)) << 4));
        int rb = wc * 64 + m * 16 + (lane & 15);
        bf[m] = *(const short8v*)(Bs + rb * 128 + ((p ^ (rb & 7)) << 4));
      }
#pragma unroll
      for (int m = 0; m < 4; m++)
#pragma unroll
        for (int n = 0; n < 4; n++)
          acc[m][n] = __builtin_amdgcn_mfma_f32_16x16x32_bf16(
              af[m], bf[n], acc[m][n], 0, 0, 0);
    }
  }
#pragma unroll
  for (int m = 0; m < 4; m++) {
#pragma unroll
    for (int n = 0; n < 4; n++) {
      int col = col0 + wc * 64 + n * 16 + (lane & 15);
      float bv = BIAS ? bias[col] : 0.f;
#pragma unroll
      for (int q = 0; q < 4; q++) {
        int row = row0 + wr * 64 + m * 16 + (lane >> 4) * 4 + q;
        float v = fmaxf(acc[m][n][q] + bv, 0.f);
        if constexpr (OUTBF16) {
          ((__hip_bfloat16*)Cv)[(size_t)row * N + col] = __float2bfloat16(v);
        } else {
          ((float*)Cv)[(size_t)row * N + col] = v;
        }
      }
    }
  }
}

// dst family fused: n2[v] = sum_t cnt[v,t]*relu(x[v] @ Wd_t); writes bf16 into
// nb16 cols [768,1536). Same tile structure, t-loop in-kernel.
__global__ __launch_bounds__(256) void gemm_dst_kernel(
    const __hip_bfloat16* __restrict__ A, const __hip_bfloat16* __restrict__ WcTd,
    const int* __restrict__ cnt4, __hip_bfloat16* __restrict__ nb16) {
  const int K = D_;
  __shared__ char lds[32768];
  char* As = lds;
  char* Bs = lds + 16384;
  int tid = threadIdx.x;
  int lane = tid & 63;
  int wv = tid >> 6;
  int wr = wv >> 1, wc = wv & 1;
  int nwg = gridDim.x * gridDim.y;
  int id = blockIdx.y * gridDim.x + blockIdx.x;
  int s = (id & 7) * (nwg >> 3) + (id >> 3);
  int bx = s % gridDim.x, by = s / gridDim.x;
  int row0 = by * 128, col0 = bx * 128;
  int r_ = tid >> 3;
  int s_ = tid & 7;

  floatx4 sacc[4][4];
#pragma unroll
  for (int i = 0; i < 4; i++)
#pragma unroll
    for (int j = 0; j < 4; j++) sacc[i][j] = floatx4{0.f, 0.f, 0.f, 0.f};

  for (int t = 0; t < 4; t++) {
    const __hip_bfloat16* BT = WcTd + (size_t)t * DSQ_;
    floatx4 acc[4][4];
#pragma unroll
    for (int i = 0; i < 4; i++)
#pragma unroll
      for (int j = 0; j < 4; j++) acc[i][j] = floatx4{0.f, 0.f, 0.f, 0.f};
    for (int k0 = 0; k0 < K; k0 += 64) {
      __syncthreads();
#pragma unroll
      for (int is = 0; is < 4; is++) {
        int r = is * 32 + r_;
        int sp = s_ ^ (r & 7);
        gld16(A  + (size_t)(row0 + r) * K + k0 + sp * 8, As + is * 4096 + tid * 16);
        gld16(BT + (size_t)(col0 + r) * K + k0 + sp * 8, Bs + is * 4096 + tid * 16);
      }
      __syncthreads();
#pragma unroll
      for (int kk = 0; kk < 64; kk += 32) {
        int p = (kk >> 3) + (lane >> 4);
        short8v af[4], bf[4];
#pragma unroll
        for (int m = 0; m < 4; m++) {
          int ra = wr * 64 + m * 16 + (lane & 15);
          af[m] = *(const short8v*)(As + ra * 128 + ((p ^ (ra & 7)) << 4));
          int rb = wc * 64 + m * 16 + (lane & 15);
          bf[m] = *(const short8v*)(Bs + rb * 128 + ((p ^ (rb & 7)) << 4));
        }
#pragma unroll
        for (int m = 0; m < 4; m++)
#pragma unroll
          for (int n = 0; n < 4; n++)
            acc[m][n] = __builtin_amdgcn_mfma_f32_16x16x32_bf16(
                af[m], bf[n], acc[m][n], 0, 0, 0);
      }
    }
#pragma unroll
    for (int m = 0; m < 4; m++)
#pragma unroll
      for (int q = 0; q < 4; q++) {
        int row = row0 + wr * 64 + m * 16 + (lane >> 4) * 4 + q;
        float c = (float)cnt4[row * 4 + t];
#pragma unroll
        for (int n = 0; n < 4; n++)
          sacc[m][n][q] += c * fmaxf(acc[m][n][q], 0.f);
      }
  }
#pragma unroll
  for (int m = 0; m < 4; m++)
#pragma unroll
    for (int n = 0; n < 4; n++) {
      int col = col0 + wc * 64 + n * 16 + (lane & 15);
#pragma unroll
      for (int q = 0; q < 4; q++) {
        int row = row0 + wr * 64 + m * 16 + (lane >> 4) * 4 + q;
        nb16[(size_t)row * D2_ + D_ + col] = __float2bfloat16(sacc[m][n][q]);
      }
    }
}

__global__ __launch_bounds__(256) void norm_kernel(
    const float* __restrict__ z, float* __restrict__ out) {
  int v = blockIdx.x, tid = threadIdx.x;
  const float* zr = z + (size_t)v * D_;
  float e0 = zr[tid], e1 = zr[tid + 256], e2 = zr[tid + 512];
  float q = e0 * e0 + e1 * e1 + e2 * e2;
  __shared__ float red[4];
  __shared__ float sc;
  float wq = wave_sum(q);
  int lane = tid & 63, w = tid >> 6;
  if (lane == 0) red[w] = wq;
  __syncthreads();
  if (tid == 0) {
    float S = red[0] + red[1] + red[2] + red[3];
    float norm = sqrtf(S);
    sc = (norm == 0.f) ? 1.f : (1.f / norm);
  }
  __syncthreads();
  float s = sc;
  float* orow = out + (size_t)v * D_;
  orow[tid]       = e0 * s;
  orow[tid + 256] = e1 * s;
  orow[tid + 512] = e2 * s;
}

extern "C" void kernel_launch(void* const* d_in, const int* in_sizes, int n_in,
                              void* d_out, int out_size, void* d_ws,
                              size_t ws_size, hipStream_t stream) {
  (void)in_sizes; (void)n_in; (void)out_size; (void)ws_size;
  const float* h      = (const float*)d_in[0];
  const float* W_text = (const float*)d_in[1];
  const float* c_text = (const float*)d_in[2];
  const float* W_user = (const float*)d_in[3];
  const float* c_user = (const float*)d_in[4];
  const float* W_dst  = (const float*)d_in[5];
  const float* c_dst  = (const float*)d_in[6];
  const float* gamma  = (const float*)d_in[7];
  const float* beta   = (const float*)d_in[8];
  const float* W_lin  = (const float*)d_in[9];
  const float* b_lin  = (const float*)d_in[10];
  const int* src      = (const int*)d_in[11];
  const int* dst      = (const int*)d_in[12];
  const int* etype    = (const int*)d_in[13];
  const int* hete     = (const int*)d_in[14];
  float* out          = (float*)d_out;

  char* ws = (char*)d_ws;
  __hip_bfloat16* xb   = (__hip_bfloat16*)(ws + OFF_XB);
  __hip_bfloat16* WcT  = (__hip_bfloat16*)(ws + OFF_WCT);
  __hip_bfloat16* WlT  = (__hip_bfloat16*)(ws + OFF_WLT);
  __hip_bfloat16* nb16 = (__hip_bfloat16*)(ws + OFF_NB16);
  __hip_bfloat16* H3   = (__hip_bfloat16*)(ws + OFF_H3);
  float* zbuf          = (float*)(ws + OFF_ZB);
  float* n1f           = (float*)(ws + OFF_N1F);
  int* target   = (int*)(ws + OFF_TG);
  int* payload  = (int*)(ws + OFF_PAY);
  int* cnt4     = (int*)(ws + OFF_CNT);
  int* base     = (int*)(ws + OFF_BASE);
  int* cursor   = (int*)(ws + OFF_CUR);
  int* blockcnt = (int*)(ws + OFF_BC);
  int* scanout  = (int*)(ws + OFF_SCAN);

  hipMemsetAsync(cnt4, 0, (size_t)N_ * 4 * 4, stream);
  hipMemsetAsync(cursor, 0, (size_t)N_ * 4, stream);

  combine_wt_kernel<<<dim3(DSQ_ / 256, 12), 256, 0, stream>>>(
      W_text, c_text, W_user, c_user, W_dst, c_dst, WcT);
  wlint_kernel<<<(D2_ * D_) / 256, 256, 0, stream>>>(W_lin, WlT);
  ln_kernel<<<N_, 256, 0, stream>>>(h, gamma, beta, xb);
  edge_a_kernel<<<E_ / 256, 256, 0, stream>>>(hete, dst, etype, blockcnt, cnt4);
  scan_kernel<<<1, 512, 0, stream>>>(blockcnt, scanout);
  edge_b_kernel<<<E_ / 256, 256, 0, stream>>>(hete, dst, scanout, target);
  base_scan_kernel<<<1, 1024, 0, stream>>>(cnt4, base);
  edge_sort_kernel<<<E_ / 256, 256, 0, stream>>>(target, src, etype, hete,
                                                 base, cursor, payload);

  // dst family fused -> nb16 cols [768,1536)
  gemm_dst_kernel<<<dim3(D_ / 128, N_ / 128), 256, 0, stream>>>(
      xb, WcT + (size_t)8 * DSQ_, cnt4, nb16);

  // src families in 3 passes of {3,3,2} groups; gather accumulates n1
  const int g0s[3] = {0, 3, 6};
  const int gns[3] = {3, 3, 2};
  for (int pass = 0; pass < 3; pass++) {
    for (int gi = 0; gi < gns[pass]; gi++) {
      int g = g0s[pass] + gi;
      gemm_mfma_kernel<false, true><<<dim3(D_ / 128, N_ / 128), 256, 0, stream>>>(
          xb, WcT + (size_t)g * DSQ_, nullptr, H3 + (size_t)gi * N_ * D_,
          N_, D_, D_);
    }
    if (pass == 0)
      gather_n1_kernel<true, false><<<N_ / 4, 256, 0, stream>>>(
          H3, base, payload, n1f, nb16, g0s[pass], gns[pass]);
    else if (pass == 1)
      gather_n1_kernel<false, false><<<N_ / 4, 256, 0, stream>>>(
          H3, base, payload, n1f, nb16, g0s[pass], gns[pass]);
    else
      gather_n1_kernel<false, true><<<N_ / 4, 256, 0, stream>>>(
          H3, base, payload, n1f, nb16, g0s[pass], gns[pass]);
  }

  // z = relu(nb16 @ W_lin + b_lin) -> zbuf (reuses H3 region), then norm
  gemm_mfma_kernel<true, false><<<dim3(D_ / 128, N_ / 128), 256, 0, stream>>>(
      nb16, WlT, b_lin, zbuf, N_, D_, D2_);
  norm_kernel<<<N_, 256, 0, stream>>>(zbuf, out);
}

// Round 7
// 509.563 us; speedup vs baseline: 7.9786x; 1.2012x over previous
//
#include <hip/hip_runtime.h>
#include <hip/hip_bf16.h>
#include <cstdint>

static constexpr int N_  = 16384;
static constexpr int E_  = 131072;
static constexpr int D_  = 768;
static constexpr int D2_ = 1536;
static constexpr int DSQ_ = D_ * D_;

// ---------------- workspace layout (bytes), total ~219.3 MB ----------------
static constexpr size_t OFF_XB   = 0;            // N*D bf16    = 25165824
static constexpr size_t OFF_WCT  = 25165824;     // 12*D*D bf16 = 14155776
static constexpr size_t OFF_WLT  = 39321600;     // D*2D bf16   = 2359296
static constexpr size_t OFF_NB16 = 41680896;     // N*2D bf16   = 50331648
static constexpr size_t OFF_H4   = 92012544;     // 4 * N*D bf16 = 100663296
static constexpr size_t OFF_ZB   = 92012544;     // N*D fp32 (reuses H4 after gathers)
static constexpr size_t OFF_N1C  = 192675840;    // N*D bf16 carry = 25165824
static constexpr size_t OFF_TG   = 217841664;    // E int32     = 524288
static constexpr size_t OFF_PAY  = 218365952;    // E int32     = 524288
static constexpr size_t OFF_CNT  = 218890240;    // N*4 int32   = 262144
static constexpr size_t OFF_BASE = 219152384;    // (N+1) int32, padded to 65552
static constexpr size_t OFF_CUR  = 219217936;    // N int32     = 65536
static constexpr size_t OFF_BC   = 219283472;    // 512 int32
static constexpr size_t OFF_SCAN = 219285520;    // 513 int32

typedef __attribute__((ext_vector_type(8))) short short8v;
typedef __attribute__((ext_vector_type(4))) float floatx4;

__device__ __forceinline__ void gld16(const void* g, void* l) {
  __builtin_amdgcn_global_load_lds(
      (const __attribute__((address_space(1))) unsigned int*)g,
      (__attribute__((address_space(3))) unsigned int*)l, 16, 0, 0);
}

__device__ __forceinline__ float b2f(short u) {
  union { unsigned int i; float f; } x;
  x.i = ((unsigned int)(unsigned short)u) << 16;
  return x.f;
}

__device__ __forceinline__ float wave_sum(float v) {
#pragma unroll
  for (int o = 32; o; o >>= 1) v += __shfl_down(v, o, 64);
  return v;
}

// WcT[ft][h][d] = sum_b coeff_f[t,b] * W_f[b][d][h]  (bf16, transposed)
__global__ __launch_bounds__(256) void combine_wt_kernel(
    const float* __restrict__ Wt, const float* __restrict__ ct,
    const float* __restrict__ Wu, const float* __restrict__ cu,
    const float* __restrict__ Wd, const float* __restrict__ cd,
    __hip_bfloat16* __restrict__ WcT) {
  int i  = blockIdx.x * 256 + threadIdx.x;   // < D*D, i = d*768 + h
  int ft = blockIdx.y;                        // 0..11
  int f = ft >> 2, t = ft & 3;
  const float* W = (f == 0) ? Wt : ((f == 1) ? Wu : Wd);
  const float* c = ((f == 0) ? ct : ((f == 1) ? cu : cd)) + t * 3;
  float v = c[0] * W[i] + c[1] * W[DSQ_ + i] + c[2] * W[2 * DSQ_ + i];
  int d = i / D_, h = i % D_;
  WcT[(size_t)ft * DSQ_ + (size_t)h * D_ + d] = __float2bfloat16(v);
}

// W_linT[h][k] = W_lin[k][h] (bf16)
__global__ __launch_bounds__(256) void wlint_kernel(
    const float* __restrict__ W, __hip_bfloat16* __restrict__ WT) {
  int i = blockIdx.x * 256 + threadIdx.x;    // < 2D*D, i = k*768 + h
  int k = i / D_, h = i % D_;
  WT[(size_t)h * D2_ + k] = __float2bfloat16(W[i]);
}

__global__ __launch_bounds__(256) void ln_kernel(
    const float* __restrict__ h, const float* __restrict__ gamma,
    const float* __restrict__ beta, __hip_bfloat16* __restrict__ x) {
  int v = blockIdx.x, tid = threadIdx.x;
  const float* hr = h + (size_t)v * D_;
  float e0 = hr[tid], e1 = hr[tid + 256], e2 = hr[tid + 512];
  float s = e0 + e1 + e2;
  float q = e0 * e0 + e1 * e1 + e2 * e2;
  __shared__ float red[8];
  __shared__ float mv[2];
  float ws_ = wave_sum(s), wq = wave_sum(q);
  int lane = tid & 63, w = tid >> 6;
  if (lane == 0) { red[w] = ws_; red[4 + w] = wq; }
  __syncthreads();
  if (tid == 0) {
    float S = red[0] + red[1] + red[2] + red[3];
    float Q = red[4] + red[5] + red[6] + red[7];
    float mu = S * (1.0f / D_);
    float var = Q * (1.0f / D_) - mu * mu;
    mv[0] = mu;
    mv[1] = rsqrtf(var + 1e-5f);
  }
  __syncthreads();
  float mu = mv[0], rstd = mv[1];
  __hip_bfloat16* xr = x + (size_t)v * D_;
  xr[tid]       = __float2bfloat16((e0 - mu) * rstd * gamma[tid]       + beta[tid]);
  xr[tid + 256] = __float2bfloat16((e1 - mu) * rstd * gamma[tid + 256] + beta[tid + 256]);
  xr[tid + 512] = __float2bfloat16((e2 - mu) * rstd * gamma[tid + 512] + beta[tid + 512]);
}

// per-block hete counts + (dst,etype) histogram
__global__ __launch_bounds__(256) void edge_a_kernel(
    const int* __restrict__ hete, const int* __restrict__ dst,
    const int* __restrict__ etype, int* __restrict__ blockcnt,
    int* __restrict__ cnt4) {
  int j = blockIdx.x * 256 + threadIdx.x;
  int flag = hete[j] > 0;
  unsigned long long m = __ballot(flag);
  __shared__ int wsum[4];
  int lane = threadIdx.x & 63, w = threadIdx.x >> 6;
  if (lane == 0) wsum[w] = __popcll(m);
  __syncthreads();
  if (threadIdx.x == 0)
    blockcnt[blockIdx.x] = wsum[0] + wsum[1] + wsum[2] + wsum[3];
  atomicAdd(&cnt4[dst[j] * 4 + etype[j]], 1);
}

// single-block scan over 512 block counts -> exclusive offsets + total K
__global__ __launch_bounds__(512) void scan_kernel(
    const int* __restrict__ blockcnt, int* __restrict__ scanout) {
  __shared__ int s[512];
  int t = threadIdx.x;
  int v = blockcnt[t];
  s[t] = v;
  __syncthreads();
  for (int o = 1; o < 512; o <<= 1) {
    int add = (t >= o) ? s[t - o] : 0;
    __syncthreads();
    s[t] += add;
    __syncthreads();
  }
  scanout[t] = s[t] - v;             // exclusive prefix
  if (t == 511) scanout[512] = s[511];  // total hete count K
}

// target[j] = dst[perm_inv[j]]
__global__ __launch_bounds__(256) void edge_b_kernel(
    const int* __restrict__ hete, const int* __restrict__ dst,
    const int* __restrict__ scanout, int* __restrict__ target) {
  int j = blockIdx.x * 256 + threadIdx.x;
  int flag = hete[j] > 0;
  unsigned long long m = __ballot(flag);
  __shared__ int wsum[4];
  int lane = threadIdx.x & 63, w = threadIdx.x >> 6;
  if (lane == 0) wsum[w] = __popcll(m);
  __syncthreads();
  int wpre = 0;
#pragma unroll
  for (int i = 0; i < 4; i++) wpre += (i < w) ? wsum[i] : 0;
  int lpre = __popcll(m & ((1ull << lane) - 1ull));
  int hcum = scanout[blockIdx.x] + wpre + lpre;  // # hete edges with idx < j
  int K = scanout[512];
  int e = flag ? hcum : (K + j - hcum);
  target[j] = dst[e];
}

// base[v] = exclusive prefix of deg[v] = sum_t cnt4[v,t]; base[N]=E
__global__ __launch_bounds__(1024) void base_scan_kernel(
    const int* __restrict__ cnt4, int* __restrict__ base) {
  __shared__ int s[1024];
  int t = threadIdx.x;
  int loc[16];
  int sum = 0;
#pragma unroll
  for (int i = 0; i < 16; i++) {
    int v = t * 16 + i;
    int d = cnt4[v * 4] + cnt4[v * 4 + 1] + cnt4[v * 4 + 2] + cnt4[v * 4 + 3];
    loc[i] = sum;
    sum += d;
  }
  s[t] = sum;
  __syncthreads();
  for (int o = 1; o < 1024; o <<= 1) {
    int add = (t >= o) ? s[t - o] : 0;
    __syncthreads();
    s[t] += add;
    __syncthreads();
  }
  int pre = t ? s[t - 1] : 0;
#pragma unroll
  for (int i = 0; i < 16; i++) base[t * 16 + i] = pre + loc[i];
  if (t == 1023) base[N_] = s[1023];
}

// payload[base[target[j]] + cursor++] = g<<14 | src[j]
__global__ __launch_bounds__(256) void edge_sort_kernel(
    const int* __restrict__ target, const int* __restrict__ src,
    const int* __restrict__ etype, const int* __restrict__ hete,
    const int* __restrict__ base, int* __restrict__ cursor,
    int* __restrict__ payload) {
  int j = blockIdx.x * 256 + threadIdx.x;
  int v = target[j];
  int p = base[v] + atomicAdd(&cursor[v], 1);
  int g = ((hete[j] > 0) ? 0 : 4) + etype[j];
  payload[p] = (g << 14) | src[j];
}

// one wave per node; groups [g0, g0+4). Lane owns elems [lane*8,+8) and
// [512+lane*4,+4) -> 16B + 8B vector loads per edge row (G13).
template <bool FIRST>
__global__ __launch_bounds__(256) void gather_n1_kernel(
    const __hip_bfloat16* __restrict__ H, const int* __restrict__ base,
    const int* __restrict__ payload, __hip_bfloat16* __restrict__ n1c,
    __hip_bfloat16* __restrict__ nb16, int g0) {
  int wv = threadIdx.x >> 6, lane = threadIdx.x & 63;
  int v = blockIdx.x * 4 + wv;
  int b0 = base[v], b1 = base[v + 1];
  float acc[12];
  if (FIRST) {
#pragma unroll
    for (int i = 0; i < 12; i++) acc[i] = 0.f;
  } else {
    short8v a8 = *(const short8v*)(n1c + (size_t)v * D_ + lane * 8);
    short4  b4 = *(const short4*)(n1c + (size_t)v * D_ + 512 + lane * 4);
#pragma unroll
    for (int i = 0; i < 8; i++) acc[i] = b2f(a8[i]);
    acc[8] = b2f(b4.x); acc[9] = b2f(b4.y);
    acc[10] = b2f(b4.z); acc[11] = b2f(b4.w);
  }
  for (int idx = b0; idx < b1; ++idx) {
    int pl = payload[idx];
    int g = (pl >> 14) - g0;
    if ((unsigned)g > 3u) continue;
    const __hip_bfloat16* row = H + ((size_t)g * N_ + (pl & 16383)) * D_;
    short8v a8 = *(const short8v*)(row + lane * 8);
    short4  b4 = *(const short4*)(row + 512 + lane * 4);
#pragma unroll
    for (int i = 0; i < 8; i++) acc[i] += b2f(a8[i]);
    acc[8] += b2f(b4.x); acc[9] += b2f(b4.y);
    acc[10] += b2f(b4.z); acc[11] += b2f(b4.w);
  }
  __hip_bfloat16 o[12];
#pragma unroll
  for (int i = 0; i < 12; i++) o[i] = __float2bfloat16(acc[i]);
  if (FIRST) {
    *(short8v*)(n1c + (size_t)v * D_ + lane * 8) = *(const short8v*)o;
    *(short4*)(n1c + (size_t)v * D_ + 512 + lane * 4) = *(const short4*)(o + 8);
  } else {
    *(short8v*)(nb16 + (size_t)v * D2_ + lane * 8) = *(const short8v*)o;
    *(short4*)(nb16 + (size_t)v * D2_ + 512 + lane * 4) = *(const short4*)(o + 8);
  }
}

// nb16[v][768+k] = sum_t cnt4[v,t] * H4[t][v][k]; thread per 8 elems
__global__ __launch_bounds__(256) void combine_n2_kernel(
    const __hip_bfloat16* __restrict__ H4, const int* __restrict__ cnt4,
    __hip_bfloat16* __restrict__ nb16) {
  size_t i = ((size_t)blockIdx.x * 256 + threadIdx.x) * 8;  // < N*D
  int v = (int)(i / D_);
  int k = (int)(i % D_);
  float acc[8] = {0.f, 0.f, 0.f, 0.f, 0.f, 0.f, 0.f, 0.f};
#pragma unroll
  for (int t = 0; t < 4; t++) {
    float c = (float)cnt4[v * 4 + t];
    if (c != 0.f) {
      short8v hv = *(const short8v*)(H4 + (size_t)t * N_ * D_ + i);
#pragma unroll
      for (int j = 0; j < 8; j++) acc[j] += c * b2f(hv[j]);
    }
  }
  __hip_bfloat16 o[8];
#pragma unroll
  for (int j = 0; j < 8; j++) o[j] = __float2bfloat16(acc[j]);
  *(short8v*)(nb16 + (size_t)v * D2_ + D_ + k) = *(const short8v*)o;
}

// C[z][M,N] = relu(A[M,K] @ BT[z][N,K]^T (+bias)), batched over blockIdx.z.
// 128x128 tile, BK=64, 4 waves (2x2), 16x16x32 bf16 MFMA, XOR-swizzled LDS,
// XCD-chunked block swizzle within each z slice.
template <bool BIAS, bool OUTBF16>
__global__ __launch_bounds__(256) void gemm_mfma_kernel(
    const __hip_bfloat16* __restrict__ A, const __hip_bfloat16* __restrict__ BT0,
    const float* __restrict__ bias, void* __restrict__ Cv,
    int M, int N, int K, size_t strideB, size_t strideC) {
  const __hip_bfloat16* BT = BT0 + (size_t)blockIdx.z * strideB;
  __shared__ char lds[32768];
  char* As = lds;
  char* Bs = lds + 16384;
  int tid = threadIdx.x;
  int lane = tid & 63;
  int wv = tid >> 6;
  int wr = wv >> 1, wc = wv & 1;
  int nwg = gridDim.x * gridDim.y;
  int id = blockIdx.y * gridDim.x + blockIdx.x;
  int s = (id & 7) * (nwg >> 3) + (id >> 3);
  int bx = s % gridDim.x, by = s / gridDim.x;
  int row0 = by * 128, col0 = bx * 128;
  int r_ = tid >> 3;
  int s_ = tid & 7;

  floatx4 acc[4][4];
#pragma unroll
  for (int i = 0; i < 4; i++)
#pragma unroll
    for (int j = 0; j < 4; j++) acc[i][j] = floatx4{0.f, 0.f, 0.f, 0.f};

  for (int k0 = 0; k0 < K; k0 += 64) {
    __syncthreads();
#pragma unroll
    for (int is = 0; is < 4; is++) {
      int r = is * 32 + r_;
      int sp = s_ ^ (r & 7);
      gld16(A  + (size_t)(row0 + r) * K + k0 + sp * 8, As + is * 4096 + tid * 16);
      gld16(BT + (size_t)(col0 + r) * K + k0 + sp * 8, Bs + is * 4096 + tid * 16);
    }
    __syncthreads();
#pragma unroll
    for (int kk = 0; kk < 64; kk += 32) {
      int p = (kk >> 3) + (lane >> 4);
      short8v af[4], bf[4];
#pragma unroll
      for (int m = 0; m < 4; m++) {
        int ra = wr * 64 + m * 16 + (lane & 15);
        af[m] = *(const short8v*)(As + ra * 128 + ((p ^ (ra & 7)) << 4));
        int rb = wc * 64 + m * 16 + (lane & 15);
        bf[m] = *(const short8v*)(Bs + rb * 128 + ((p ^ (rb & 7)) << 4));
      }
#pragma unroll
      for (int m = 0; m < 4; m++)
#pragma unroll
        for (int n = 0; n < 4; n++)
          acc[m][n] = __builtin_amdgcn_mfma_f32_16x16x32_bf16(
              af[m], bf[n], acc[m][n], 0, 0, 0);
    }
  }
#pragma unroll
  for (int m = 0; m < 4; m++) {
#pragma unroll
    for (int n = 0; n < 4; n++) {
      int col = col0 + wc * 64 + n * 16 + (lane & 15);
      float bv = BIAS ? bias[col] : 0.f;
#pragma unroll
      for (int q = 0; q < 4; q++) {
        int row = row0 + wr * 64 + m * 16 + (lane >> 4) * 4 + q;
        float v = fmaxf(acc[m][n][q] + bv, 0.f);
        if constexpr (OUTBF16) {
          ((__hip_bfloat16*)Cv + (size_t)blockIdx.z * strideC)
              [(size_t)row * N + col] = __float2bfloat16(v);
        } else {
          ((float*)Cv + (size_t)blockIdx.z * strideC)
              [(size_t)row * N + col] = v;
        }
      }
    }
  }
}

__global__ __launch_bounds__(256) void norm_kernel(
    const float* __restrict__ z, float* __restrict__ out) {
  int v = blockIdx.x, tid = threadIdx.x;
  const float* zr = z + (size_t)v * D_;
  float e0 = zr[tid], e1 = zr[tid + 256], e2 = zr[tid + 512];
  float q = e0 * e0 + e1 * e1 + e2 * e2;
  __shared__ float red[4];
  __shared__ float sc;
  float wq = wave_sum(q);
  int lane = tid & 63, w = tid >> 6;
  if (lane == 0) red[w] = wq;
  __syncthreads();
  if (tid == 0) {
    float S = red[0] + red[1] + red[2] + red[3];
    float norm = sqrtf(S);
    sc = (norm == 0.f) ? 1.f : (1.f / norm);
  }
  __syncthreads();
  float s = sc;
  float* orow = out + (size_t)v * D_;
  orow[tid]       = e0 * s;
  orow[tid + 256] = e1 * s;
  orow[tid + 512] = e2 * s;
}

extern "C" void kernel_launch(void* const* d_in, const int* in_sizes, int n_in,
                              void* d_out, int out_size, void* d_ws,
                              size_t ws_size, hipStream_t stream) {
  (void)in_sizes; (void)n_in; (void)out_size; (void)ws_size;
  const float* h      = (const float*)d_in[0];
  const float* W_text = (const float*)d_in[1];
  const float* c_text = (const float*)d_in[2];
  const float* W_user = (const float*)d_in[3];
  const float* c_user = (const float*)d_in[4];
  const float* W_dst  = (const float*)d_in[5];
  const float* c_dst  = (const float*)d_in[6];
  const float* gamma  = (const float*)d_in[7];
  const float* beta   = (const float*)d_in[8];
  const float* W_lin  = (const float*)d_in[9];
  const float* b_lin  = (const float*)d_in[10];
  const int* src      = (const int*)d_in[11];
  const int* dst      = (const int*)d_in[12];
  const int* etype    = (const int*)d_in[13];
  const int* hete     = (const int*)d_in[14];
  float* out          = (float*)d_out;

  char* ws = (char*)d_ws;
  __hip_bfloat16* xb   = (__hip_bfloat16*)(ws + OFF_XB);
  __hip_bfloat16* WcT  = (__hip_bfloat16*)(ws + OFF_WCT);
  __hip_bfloat16* WlT  = (__hip_bfloat16*)(ws + OFF_WLT);
  __hip_bfloat16* nb16 = (__hip_bfloat16*)(ws + OFF_NB16);
  __hip_bfloat16* H4   = (__hip_bfloat16*)(ws + OFF_H4);
  float* zbuf          = (float*)(ws + OFF_ZB);
  __hip_bfloat16* n1c  = (__hip_bfloat16*)(ws + OFF_N1C);
  int* target   = (int*)(ws + OFF_TG);
  int* payload  = (int*)(ws + OFF_PAY);
  int* cnt4     = (int*)(ws + OFF_CNT);
  int* base     = (int*)(ws + OFF_BASE);
  int* cursor   = (int*)(ws + OFF_CUR);
  int* blockcnt = (int*)(ws + OFF_BC);
  int* scanout  = (int*)(ws + OFF_SCAN);

  hipMemsetAsync(cnt4, 0, (size_t)N_ * 4 * 4, stream);
  hipMemsetAsync(cursor, 0, (size_t)N_ * 4, stream);

  combine_wt_kernel<<<dim3(DSQ_ / 256, 12), 256, 0, stream>>>(
      W_text, c_text, W_user, c_user, W_dst, c_dst, WcT);
  wlint_kernel<<<(D2_ * D_) / 256, 256, 0, stream>>>(W_lin, WlT);
  ln_kernel<<<N_, 256, 0, stream>>>(h, gamma, beta, xb);
  edge_a_kernel<<<E_ / 256, 256, 0, stream>>>(hete, dst, etype, blockcnt, cnt4);
  scan_kernel<<<1, 512, 0, stream>>>(blockcnt, scanout);
  edge_b_kernel<<<E_ / 256, 256, 0, stream>>>(hete, dst, scanout, target);
  base_scan_kernel<<<1, 1024, 0, stream>>>(cnt4, base);
  edge_sort_kernel<<<E_ / 256, 256, 0, stream>>>(target, src, etype, hete,
                                                 base, cursor, payload);

  const size_t HSTRIDE = (size_t)N_ * D_;

  // dst family: 4 GEMMs batched (z) -> H4, then weighted combine into nb16
  gemm_mfma_kernel<false, true>
      <<<dim3(D_ / 128, N_ / 128, 4), 256, 0, stream>>>(
          xb, WcT + (size_t)8 * DSQ_, nullptr, H4, N_, D_, D_, DSQ_, HSTRIDE);
  combine_n2_kernel<<<(N_ * D_) / (256 * 8), 256, 0, stream>>>(H4, cnt4, nb16);

  // src families: 2 passes of 4 groups each
  gemm_mfma_kernel<false, true>
      <<<dim3(D_ / 128, N_ / 128, 4), 256, 0, stream>>>(
          xb, WcT, nullptr, H4, N_, D_, D_, DSQ_, HSTRIDE);
  gather_n1_kernel<true><<<N_ / 4, 256, 0, stream>>>(H4, base, payload, n1c,
                                                     nb16, 0);
  gemm_mfma_kernel<false, true>
      <<<dim3(D_ / 128, N_ / 128, 4), 256, 0, stream>>>(
          xb, WcT + (size_t)4 * DSQ_, nullptr, H4, N_, D_, D_, DSQ_, HSTRIDE);
  gather_n1_kernel<false><<<N_ / 4, 256, 0, stream>>>(H4, base, payload, n1c,
                                                      nb16, 4);

  // z = relu(nb16 @ W_lin + b_lin) -> zbuf (reuses H4), then norm
  gemm_mfma_kernel<true, false>
      <<<dim3(D_ / 128, N_ / 128, 1), 256, 0, stream>>>(
          nb16, WlT, b_lin, zbuf, N_, D_, D2_, 0, 0);
  norm_kernel<<<N_, 256, 0, stream>>>(zbuf, out);
}